// Round 1
// baseline (904.086 us; speedup 1.0000x reference)
//
#include <hip/hip_runtime.h>

// Binary conv2d: x (8,16,1024,1024) fp32, w (16,16,3,3) in {0,1} -> decode
// to +/-1, stride (2,2), pad (1,1) zeros => out (8,16,512,512) fp32.
//
// Memory-bound problem: 512 MiB read + 128 MiB write => ~106 us floor at
// 6.3 TB/s. Compute floor 61 us IF each tap is one v_fmac with SGPR weight.

#define IN_H   1024
#define IN_W   1024
#define OUT_H  512
#define OUT_W  512
#define C_IN   16
#define C_OUT  16

#define TILE     16          // 16x16 output pixels per block
#define TIN      33          // input tile span: 2*16+1
#define TSTRIDE  33          // LDS row stride (words)

// Pre-kernel: decode {0,1} -> {+1,-1} and transpose OIHW -> [ci][tap][co]
// so the 16 co-weights per (ci,tap) are contiguous (s_load_dwordx16-able).
__global__ void decode_weights(const float* __restrict__ w,
                               float* __restrict__ wdec) {
    int i = blockIdx.x * blockDim.x + threadIdx.x;   // over 16*9*16 = 2304
    if (i >= C_IN * 9 * C_OUT) return;
    int co  = i & 15;
    int t   = i >> 4;        // ci*9 + tap
    int tap = t % 9;
    int ci  = t / 9;
    float v = w[(co * C_IN + ci) * 9 + tap];
    wdec[i] = (v == 1.0f) ? 1.0f : -1.0f;
}

__global__ __launch_bounds__(256)
void binconv(const float* __restrict__ x,
             const float* __restrict__ wdec,
             float* __restrict__ out) {
    const int tx = threadIdx.x;   // 0..15
    const int ty = threadIdx.y;   // 0..15
    const int bx = blockIdx.x;    // 0..31 (ow tiles)
    const int by = blockIdx.y;    // 0..31 (oh tiles)
    const int n  = blockIdx.z;    // 0..7

    const int ow0 = bx * TILE;
    const int oh0 = by * TILE;
    const int gx0 = ow0 * 2 - 1;  // input col of tile origin (pad=1)
    const int gy0 = oh0 * 2 - 1;  // input row of tile origin

    __shared__ float tile[TIN * TSTRIDE];   // 4356 B

    float acc[C_OUT];
#pragma unroll
    for (int co = 0; co < C_OUT; ++co) acc[co] = 0.0f;

    const int tid = ty * 16 + tx;
    const float* xn = x + (size_t)n * C_IN * IN_H * IN_W;

    for (int ci = 0; ci < C_IN; ++ci) {
        if (ci) __syncthreads();   // protect previous tile reads
        const float* xc = xn + (size_t)ci * IN_H * IN_W;

        // stage 33x33 halo tile (only gy=-1 / gx=-1 can be OOB for this
        // geometry; right/bottom edges land exactly at 1023)
        for (int i = tid; i < TIN * TIN; i += 256) {
            int r = i / TIN;
            int c = i - r * TIN;
            int gy = gy0 + r;
            int gx = gx0 + c;
            float v = 0.0f;
            if ((unsigned)gy < (unsigned)IN_H && (unsigned)gx < (unsigned)IN_W)
                v = xc[gy * IN_W + gx];
            tile[r * TSTRIDE + c] = v;
        }
        __syncthreads();

        // 9 input values for this thread's output pixel
        float xv[9];
#pragma unroll
        for (int ky = 0; ky < 3; ++ky)
#pragma unroll
            for (int kx = 0; kx < 3; ++kx)
                xv[ky * 3 + kx] = tile[(ty * 2 + ky) * TSTRIDE + tx * 2 + kx];

        // 144 FMAs; weight address is block-uniform -> SMEM load + SGPR fmac
        const float* wc = wdec + ci * 9 * C_OUT;
#pragma unroll
        for (int t = 0; t < 9; ++t) {
            float xvt = xv[t];
#pragma unroll
            for (int co = 0; co < C_OUT; ++co)
                acc[co] = fmaf(wc[t * C_OUT + co], xvt, acc[co]);
        }
    }

    const int oh = oh0 + ty;
    const int ow = ow0 + tx;
    float* on = out + (size_t)n * C_OUT * OUT_H * OUT_W + oh * OUT_W + ow;
#pragma unroll
    for (int co = 0; co < C_OUT; ++co)
        on[(size_t)co * OUT_H * OUT_W] = acc[co];
}

extern "C" void kernel_launch(void* const* d_in, const int* in_sizes, int n_in,
                              void* d_out, int out_size, void* d_ws, size_t ws_size,
                              hipStream_t stream) {
    const float* x = (const float*)d_in[0];
    const float* w = (const float*)d_in[1];
    float* out = (float*)d_out;
    float* wdec = (float*)d_ws;   // 2304 floats = 9216 B

    decode_weights<<<dim3((C_IN * 9 * C_OUT + 255) / 256), dim3(256), 0, stream>>>(w, wdec);

    dim3 block(TILE, TILE, 1);
    dim3 grid(OUT_W / TILE, OUT_H / TILE, 8);
    binconv<<<grid, block, 0, stream>>>(x, wdec, out);
}

// Round 2
// 739.352 us; speedup vs baseline: 1.2228x; 1.2228x over previous
//
#include <hip/hip_runtime.h>

// Binary conv2d: x (8,16,1024,1024) fp32, w (16,16,3,3) in {0,1} decoded to
// +/-1, stride (2,2), pad (1,1) zeros => out (8,16,512,512) fp32.
//
// R2: no-LDS variant. R1 (LDS tile) was latency-bound: compiler minimized to
// 20 VGPRs by serializing ds_read->16fma per tap, + 16 barriers/block each
// draining HBM staging latency, + 1.5x LDS bank conflicts (stride-2 reads).
// Here each thread reads its 9 taps/ci straight from global (1 float2 + 1
// scalar per row, 8B-aligned); L1 serves the 2.25x neighbor overlap; no
// barriers, no LDS. Weights are block-uniform -> scalar loads (SMEM).
// __launch_bounds__(256,8): VGPR<=64 keeps 16 acc + 9 xv live, 8 waves/SIMD.

#define IN_H   1024
#define IN_W   1024
#define OUT_H  512
#define OUT_W  512
#define C_IN   16
#define C_OUT  16

// decode {0,1}->{+1,-1}, transpose OIHW -> [ci][tap][co] (co contiguous
// so per-(ci,tap) weights are an s_load_dwordx16 candidate).
__global__ void decode_weights(const float* __restrict__ w,
                               float* __restrict__ wdec) {
    int i = blockIdx.x * blockDim.x + threadIdx.x;   // 16*9*16 = 2304
    if (i >= C_IN * 9 * C_OUT) return;
    int co  = i & 15;
    int t   = i >> 4;        // ci*9 + tap
    int tap = t % 9;
    int ci  = t / 9;
    float v = w[(co * C_IN + ci) * 9 + tap];
    wdec[i] = (v == 1.0f) ? 1.0f : -1.0f;
}

__global__ __launch_bounds__(256, 8)
void binconv(const float* __restrict__ x,
             const float* __restrict__ wdec,
             float* __restrict__ out) {
    const int tx = threadIdx.x;            // 0..63  (one wave = one output row)
    const int ty = threadIdx.y;            // 0..3
    const int ow = blockIdx.x * 64 + tx;   // 0..511
    const int oh = blockIdx.y * 4 + ty;    // 0..511
    const int n  = blockIdx.z;             // 0..7

    const float* xn = x + (size_t)n * C_IN * IN_H * IN_W;
    const int gx0 = 2 * ow - 1;            // input col of kx=0 (pad=1)
    const int gy0 = 2 * oh - 1;            // input row of ky=0

    // Only ky=0 row (gy0=-1 when oh==0) and kx=0 col (gx0=-1 when ow==0) can
    // be OOB; right/bottom land exactly at 1023. Clamp addr, select 0 after.
    const bool row0_ok = (gy0 >= 0);
    const bool colm_ok = (gx0 >= 0);
    const int  gy0c    = row0_ok ? gy0 : 0;
    const int  gxmc    = colm_ok ? gx0 : 0;

    float acc[C_OUT];
#pragma unroll
    for (int co = 0; co < C_OUT; ++co) acc[co] = 0.0f;

    for (int ci = 0; ci < C_IN; ++ci) {
        const float* xc = xn + (size_t)ci * (IN_H * IN_W);

        float xv[9];
#pragma unroll
        for (int ky = 0; ky < 3; ++ky) {
            const int gy = (ky == 0) ? gy0c : (gy0 + ky);
            const float* xrow = xc + gy * IN_W;
            // cols 2*ow, 2*ow+1 : aligned float2 (gx0+1 = 2*ow is even)
            float2 f2 = *(const float2*)&xrow[gx0 + 1];
            // col 2*ow-1 (clamped to 0 for ow==0)
            float  sm = xrow[gxmc];
            const bool rok = (ky == 0) ? row0_ok : true;
            xv[ky * 3 + 0] = (rok && colm_ok) ? sm : 0.0f;
            xv[ky * 3 + 1] = rok ? f2.x : 0.0f;
            xv[ky * 3 + 2] = rok ? f2.y : 0.0f;
        }

        // 144 FMAs; wc is block-uniform -> scalar (SMEM) weight loads
        const float* wc = wdec + ci * 9 * C_OUT;
#pragma unroll
        for (int t = 0; t < 9; ++t) {
            const float xt = xv[t];
#pragma unroll
            for (int co = 0; co < C_OUT; ++co)
                acc[co] = fmaf(wc[t * C_OUT + co], xt, acc[co]);
        }
    }

    float* op = out + (size_t)n * C_OUT * OUT_H * OUT_W
                    + (size_t)oh * OUT_W + ow;
#pragma unroll
    for (int co = 0; co < C_OUT; ++co)
        op[(size_t)co * OUT_H * OUT_W] = acc[co];
}

extern "C" void kernel_launch(void* const* d_in, const int* in_sizes, int n_in,
                              void* d_out, int out_size, void* d_ws, size_t ws_size,
                              hipStream_t stream) {
    const float* x = (const float*)d_in[0];
    const float* w = (const float*)d_in[1];
    float* out = (float*)d_out;
    float* wdec = (float*)d_ws;   // 2304 floats = 9216 B

    decode_weights<<<dim3((C_IN * 9 * C_OUT + 255) / 256), dim3(256), 0, stream>>>(w, wdec);

    dim3 block(64, 4, 1);
    dim3 grid(OUT_W / 64, OUT_H / 4, 8);
    binconv<<<grid, block, 0, stream>>>(x, wdec, out);
}